// Round 3
// baseline (483.867 us; speedup 1.0000x reference)
//
#include <hip/hip_runtime.h>

namespace {

constexpr int NCOL  = 3;
constexpr int N_IN  = 4;
constexpr int N_OUT = 8;
constexpr int T_W   = 37;
constexpr int NB    = 4;
constexpr int NX    = 16384;
constexpr int MAT   = 2 * NCOL * NCOL;   // 18 floats per complex 3x3
constexpr int NTHREADS = NB * NX * 6;    // (site, column j, orientation o)
constexpr int OUT_U = NB * NX * 4 * MAT;

__device__ constexpr int SH[4] = {11, 8, 4, 0};
__device__ constexpr int DD[4] = {8, 8, 16, 16};
__device__ constexpr int SS[4] = {2048, 256, 16, 1};

template<int PAR>
__device__ __forceinline__ void load_mat18(const float* __restrict__ p, float* M) {
    if constexpr (PAR == 0) {
        float4 q0 = *(const float4*)(p + 0);
        float4 q1 = *(const float4*)(p + 4);
        float4 q2 = *(const float4*)(p + 8);
        float4 q3 = *(const float4*)(p + 12);
        float2 q4 = *(const float2*)(p + 16);
        M[0]=q0.x;  M[1]=q0.y;  M[2]=q0.z;  M[3]=q0.w;
        M[4]=q1.x;  M[5]=q1.y;  M[6]=q1.z;  M[7]=q1.w;
        M[8]=q2.x;  M[9]=q2.y;  M[10]=q2.z; M[11]=q2.w;
        M[12]=q3.x; M[13]=q3.y; M[14]=q3.z; M[15]=q3.w;
        M[16]=q4.x; M[17]=q4.y;
    } else {
        float2 q4 = *(const float2*)(p + 0);
        float4 q0 = *(const float4*)(p + 2);
        float4 q1 = *(const float4*)(p + 6);
        float4 q2 = *(const float4*)(p + 10);
        float4 q3 = *(const float4*)(p + 14);
        M[0]=q4.x;  M[1]=q4.y;
        M[2]=q0.x;  M[3]=q0.y;  M[4]=q0.z;  M[5]=q0.w;
        M[6]=q1.x;  M[7]=q1.y;  M[8]=q1.z;  M[9]=q1.w;
        M[10]=q2.x; M[11]=q2.y; M[12]=q2.z; M[13]=q2.w;
        M[14]=q3.x; M[15]=q3.y; M[16]=q3.z; M[17]=q3.w;
    }
}

__global__ __launch_bounds__(256, 4) void lconv_kernel(
    const float* __restrict__ u,
    const float* __restrict__ w,
    const float* __restrict__ wgt,
    float* __restrict__ out)
{
    __shared__ float wT[T_W][N_OUT];
    const int tid = threadIdx.x;
    for (int idx = tid; idx < T_W * N_OUT; idx += 256) {
        int uo = idx & 7;
        int v  = idx >> 3;
        wT[v][uo] = wgt[uo * T_W + v];
    }
    __syncthreads();

    const int gid = blockIdx.x * 256 + tid;

    // fused coalesced copy of u -> out[0:OUT_U)
    {
        const float4* __restrict__ u4 = (const float4*)u;
        float4* __restrict__ o4 = (float4*)out;
#pragma unroll
        for (int k = 0; k < 3; ++k) {
            int idx = gid + k * NTHREADS;
            o4[idx] = u4[idx];
        }
    }

    const int o  = gid & 1;
    const int sj = gid >> 1;
    const int j  = sj % 3;
    const int bs = sj / 3;
    const int x  = bs & (NX - 1);

    const float* __restrict__ wbase = w + (size_t)bs * (N_IN * MAT);

    float acc[N_OUT][NCOL][2];
#pragma unroll
    for (int uo = 0; uo < N_OUT; ++uo)
#pragma unroll
        for (int i = 0; i < NCOL; ++i) { acc[uo][i][0] = 0.f; acc[uo][i][1] = 0.f; }

    // term 0 (w itself): this thread covers channels 2o and 2o+1
#pragma unroll
    for (int t = 0; t < 2; ++t) {
        const int v = 2 * o + t;
        float4 lo = *(const float4*)&wT[v][0];
        float4 hi = *(const float4*)&wT[v][4];
        float cw[N_OUT] = {lo.x, lo.y, lo.z, lo.w, hi.x, hi.y, hi.z, hi.w};
#pragma unroll
        for (int i = 0; i < NCOL; ++i) {
            float2 e = *(const float2*)(wbase + v * MAT + (i * NCOL + j) * 2);
#pragma unroll
            for (int uo = 0; uo < N_OUT; ++uo) {
                acc[uo][i][0] = fmaf(cw[uo], e.x, acc[uo][i][0]);
                acc[uo][i][1] = fmaf(cw[uo], e.y, acc[uo][i][1]);
            }
        }
    }

#pragma unroll
    for (int a = 0; a < 4; ++a) {
        const int ca = (x >> SH[a]) & (DD[a] - 1);
        const int xn = o ? ((ca == 0)         ? x + (DD[a] - 1) * SS[a] : x - SS[a])
                         : ((ca == DD[a] - 1) ? x - (DD[a] - 1) * SS[a] : x + SS[a]);
        const int bsn = bs - x + xn;

        const int us = o ? bsn : bs;
        const float* __restrict__ Up = u + (size_t)us * (4 * MAT) + a * MAT;

        float U[MAT];
        if ((a & 1) == 0) load_mat18<0>(Up, U);   // a is unroll-constant: branch folds
        else              load_mat18<1>(Up, U);

        // d = column j of (o=0 ? U^H : U)
        float vr[3], vi[3];
#pragma unroll
        for (int k = 0; k < 3; ++k) {
            const int eidx = o ? (k * NCOL + j) : (j * NCOL + k);
            float2 e = *(const float2*)(Up + eidx * 2);
            vr[k] = e.x;
            vi[k] = o ? e.y : -e.y;
        }

        // Ueff[i][k]: o=0 -> U[i][k]; o=1 -> conj(U[k][i])
        float er[3][3], ei[3][3];
#pragma unroll
        for (int i = 0; i < 3; ++i)
#pragma unroll
            for (int k = 0; k < 3; ++k) {
                float r0 = U[(i * 3 + k) * 2], i0 = U[(i * 3 + k) * 2 + 1];
                float r1 = U[(k * 3 + i) * 2], i1 = U[(k * 3 + i) * 2 + 1];
                er[i][k] = o ? r1 : r0;
                ei[i][k] = o ? -i1 : i0;
            }

        const float* __restrict__ wn = w + (size_t)bsn * (N_IN * MAT);
        const int chbase = (o ? 5 + a : 1 + a) * 4;

#pragma unroll
        for (int v = 0; v < N_IN; ++v) {
            float Wn[MAT];
            if ((v & 1) == 0) load_mat18<0>(wn + v * MAT, Wn);
            else              load_mat18<1>(wn + v * MAT, Wn);

            float yr[3], yi[3];
#pragma unroll
            for (int i = 0; i < NCOL; ++i) {
                float sr = 0.f, si = 0.f;
#pragma unroll
                for (int k = 0; k < NCOL; ++k) {
                    float wr = Wn[(i * NCOL + k) * 2];
                    float wi = Wn[(i * NCOL + k) * 2 + 1];
                    sr = fmaf(wr, vr[k], sr); sr = fmaf(-wi, vi[k], sr);
                    si = fmaf(wr, vi[k], si); si = fmaf(wi, vr[k], si);
                }
                yr[i] = sr; yi[i] = si;
            }

            float cr[3], ci[3];
#pragma unroll
            for (int i = 0; i < NCOL; ++i) {
                float sr = 0.f, si = 0.f;
#pragma unroll
                for (int k = 0; k < NCOL; ++k) {
                    sr = fmaf(er[i][k], yr[k], sr); sr = fmaf(-ei[i][k], yi[k], sr);
                    si = fmaf(er[i][k], yi[k], si); si = fmaf(ei[i][k], yr[k], si);
                }
                cr[i] = sr; ci[i] = si;
            }

            const int ch = chbase + v;
            float4 lo = *(const float4*)&wT[ch][0];
            float4 hi = *(const float4*)&wT[ch][4];
            float cw[N_OUT] = {lo.x, lo.y, lo.z, lo.w, hi.x, hi.y, hi.z, hi.w};
#pragma unroll
            for (int uo = 0; uo < N_OUT; ++uo)
#pragma unroll
                for (int i = 0; i < NCOL; ++i) {
                    acc[uo][i][0] = fmaf(cw[uo], cr[i], acc[uo][i][0]);
                    acc[uo][i][1] = fmaf(cw[uo], ci[i], acc[uo][i][1]);
                }
        }
    }

    // pair reduction across orientation (adjacent lanes)
#pragma unroll
    for (int uo = 0; uo < N_OUT; ++uo)
#pragma unroll
        for (int i = 0; i < NCOL; ++i)
#pragma unroll
            for (int c = 0; c < 2; ++c)
                acc[uo][i][c] += __shfl_xor(acc[uo][i][c], 1);

    // store: thread o writes channels [4o, 4o+4)
    float4 idq = *(const float4*)&wT[36][4 * o];
    float cid[4] = {idq.x, idq.y, idq.z, idq.w};

    float* __restrict__ obase = out + (size_t)OUT_U + (size_t)bs * (N_OUT * MAT);
#pragma unroll
    for (int t = 0; t < 4; ++t)
#pragma unroll
        for (int i = 0; i < NCOL; ++i) {
            float vr_ = o ? acc[4 + t][i][0] : acc[t][i][0];
            float vi_ = o ? acc[4 + t][i][1] : acc[t][i][1];
            float2 e;
            e.x = vr_ + ((i == j) ? cid[t] : 0.f);
            e.y = vi_;
            *(float2*)(obase + (4 * o + t) * MAT + (i * NCOL + j) * 2) = e;
        }
}

} // namespace

extern "C" void kernel_launch(void* const* d_in, const int* in_sizes, int n_in,
                              void* d_out, int out_size, void* d_ws, size_t ws_size,
                              hipStream_t stream)
{
    const float* u   = (const float*)d_in[0];
    const float* w   = (const float*)d_in[1];
    const float* wgt = (const float*)d_in[2];
    float* out = (float*)d_out;

    dim3 block(256);
    dim3 grid(NTHREADS / 256);   // 1536 blocks
    lconv_kernel<<<grid, block, 0, stream>>>(u, w, wgt, out);
}

// Round 4
// 57.227 us; speedup vs baseline: 8.4553x; 8.4553x over previous
//
#include <hip/hip_runtime.h>

namespace {

constexpr int NCOL  = 3;
constexpr int N_IN  = 4;
constexpr int N_OUT = 8;
constexpr int T_W   = 37;
constexpr int NB    = 4;
constexpr int NX    = 16384;
constexpr int MAT   = 18;                 // floats per complex 3x3
constexpr int NSJ   = NB * NX * 3;        // (site, column) pairs
constexpr int NTHREADS = NSJ * 2;         // x2 orientations = 393216
constexpr int OUT_U = NB * NX * 4 * MAT;  // floats of output-0 (u passthrough)

__device__ constexpr int SH[4] = {11, 8, 4, 0};
__device__ constexpr int DD[4] = {8, 8, 16, 16};
__device__ constexpr int SS[4] = {2048, 256, 16, 1};

// Matrix base = 72 bytes * idx: 16B-alignment parity decided by idx&1 (compile-time).
template<int PAR>
__device__ __forceinline__ void load_mat18(const float* __restrict__ p, float* M) {
    if constexpr (PAR == 0) {
        float4 q0 = *(const float4*)(p + 0);
        float4 q1 = *(const float4*)(p + 4);
        float4 q2 = *(const float4*)(p + 8);
        float4 q3 = *(const float4*)(p + 12);
        float2 q4 = *(const float2*)(p + 16);
        M[0]=q0.x;  M[1]=q0.y;  M[2]=q0.z;  M[3]=q0.w;
        M[4]=q1.x;  M[5]=q1.y;  M[6]=q1.z;  M[7]=q1.w;
        M[8]=q2.x;  M[9]=q2.y;  M[10]=q2.z; M[11]=q2.w;
        M[12]=q3.x; M[13]=q3.y; M[14]=q3.z; M[15]=q3.w;
        M[16]=q4.x; M[17]=q4.y;
    } else {
        float2 q4 = *(const float2*)(p + 0);
        float4 q0 = *(const float4*)(p + 2);
        float4 q1 = *(const float4*)(p + 6);
        float4 q2 = *(const float4*)(p + 10);
        float4 q3 = *(const float4*)(p + 14);
        M[0]=q4.x;  M[1]=q4.y;
        M[2]=q0.x;  M[3]=q0.y;  M[4]=q0.z;  M[5]=q0.w;
        M[6]=q1.x;  M[7]=q1.y;  M[8]=q1.z;  M[9]=q1.w;
        M[10]=q2.x; M[11]=q2.y; M[12]=q2.z; M[13]=q2.w;
        M[14]=q3.x; M[15]=q3.y; M[16]=q3.z; M[17]=q3.w;
    }
}

// O==0: c = U * (W*d)   (rows of U);  O==1: c = U^H * (W*d)  (conj columns of U)
template<int O>
__device__ __forceinline__ void transport_col(
    const float U[18], const float vr[3], const float vi[3],
    const float W[18], float cr[3], float ci[3])
{
    float yr[3], yi[3];
#pragma unroll
    for (int i = 0; i < 3; ++i) {
        float sr = 0.f, si = 0.f;
#pragma unroll
        for (int k = 0; k < 3; ++k) {
            float wr = W[(i*3+k)*2], wi = W[(i*3+k)*2+1];
            sr = fmaf(wr, vr[k], sr); sr = fmaf(-wi, vi[k], sr);
            si = fmaf(wr, vi[k], si); si = fmaf(wi, vr[k], si);
        }
        yr[i] = sr; yi[i] = si;
    }
#pragma unroll
    for (int i = 0; i < 3; ++i) {
        float sr = 0.f, si = 0.f;
#pragma unroll
        for (int k = 0; k < 3; ++k) {
            if constexpr (O == 0) {
                float ur = U[(i*3+k)*2], ui = U[(i*3+k)*2+1];
                sr = fmaf(ur, yr[k], sr); sr = fmaf(-ui, yi[k], sr);
                si = fmaf(ur, yi[k], si); si = fmaf(ui, yr[k], si);
            } else {
                float ur = U[(k*3+i)*2], ui = U[(k*3+i)*2+1];
                sr = fmaf(ur, yr[k], sr); sr = fmaf(ui, yi[k], sr);
                si = fmaf(ur, yi[k], si); si = fmaf(-ui, yr[k], si);
            }
        }
        cr[i] = sr; ci[i] = si;
    }
}

__device__ __forceinline__ void mix(const float (*wT)[N_OUT], int ch,
    const float cr[3], const float ci[3], float acc[N_OUT][NCOL][2])
{
    float4 lo = *(const float4*)&wT[ch][0];
    float4 hi = *(const float4*)&wT[ch][4];
    const float cw[8] = {lo.x, lo.y, lo.z, lo.w, hi.x, hi.y, hi.z, hi.w};
#pragma unroll
    for (int uo = 0; uo < 8; ++uo)
#pragma unroll
        for (int i = 0; i < 3; ++i) {
            acc[uo][i][0] = fmaf(cw[uo], cr[i], acc[uo][i][0]);
            acc[uo][i][1] = fmaf(cw[uo], ci[i], acc[uo][i][1]);
        }
}

template<int O>
__device__ __forceinline__ void do_orientation(
    int x, int bs, int j,
    const float* __restrict__ u, const float* __restrict__ w,
    const float (*wT)[N_OUT], float acc[N_OUT][NCOL][2])
{
#pragma unroll
    for (int a = 0; a < 4; ++a) {
        const int ca = (x >> SH[a]) & (DD[a] - 1);
        int xn;
        if constexpr (O == 0) xn = (ca == DD[a]-1) ? x - (DD[a]-1)*SS[a] : x + SS[a];
        else                  xn = (ca == 0)       ? x + (DD[a]-1)*SS[a] : x - SS[a];
        const int bsn = bs - x + xn;
        const int us  = (O == 0) ? bs : bsn;

        const float* __restrict__ Up = u + (size_t)us * (4 * MAT) + a * MAT;
        float U[18];
        if ((a & 1) == 0) load_mat18<0>(Up, U);   // a unroll-constant: folds
        else              load_mat18<1>(Up, U);

        // d = column j of (O==0 ? U^H : U)  — from memory (L1 hit), avoids
        // runtime-indexing the U register array (rule #20)
        float vr[3], vi[3];
#pragma unroll
        for (int k = 0; k < 3; ++k) {
            const int eidx = (O == 0) ? (j*3 + k) : (k*3 + j);
            float2 e = *(const float2*)(Up + eidx * 2);
            vr[k] = e.x;
            vi[k] = (O == 0) ? -e.y : e.y;
        }

        const float* __restrict__ wn = w + (size_t)bsn * (N_IN * MAT);
        const int chbase = ((O == 0) ? (1 + a) : (5 + a)) * 4;

        // double-buffered W: next-v load issued before current-v compute
        float WA[18], WB[18], cr[3], ci[3];
        load_mat18<0>(wn + 0 * MAT, WA);
        load_mat18<1>(wn + 1 * MAT, WB);

        transport_col<O>(U, vr, vi, WA, cr, ci);   // v=0
        mix(wT, chbase + 0, cr, ci, acc);
        load_mat18<0>(wn + 2 * MAT, WA);

        transport_col<O>(U, vr, vi, WB, cr, ci);   // v=1
        mix(wT, chbase + 1, cr, ci, acc);
        load_mat18<1>(wn + 3 * MAT, WB);

        transport_col<O>(U, vr, vi, WA, cr, ci);   // v=2
        mix(wT, chbase + 2, cr, ci, acc);

        transport_col<O>(U, vr, vi, WB, cr, ci);   // v=3
        mix(wT, chbase + 3, cr, ci, acc);
    }
}

__global__ __launch_bounds__(256) void lconv_kernel(
    const float* __restrict__ u,
    const float* __restrict__ w,
    const float* __restrict__ wgt,
    float* __restrict__ out)
{
    __shared__ float  wT[T_W][N_OUT];
    __shared__ float2 red[256][13];    // 12 used + 1 pad (104B row: 8B-aligned, 4-way banks)

    const int tid = threadIdx.x;
    for (int idx = tid; idx < T_W * N_OUT; idx += 256) {
        int uo = idx & 7;
        int v  = idx >> 3;
        wT[v][uo] = wgt[uo * T_W + v];
    }
    __syncthreads();

    const int gid = blockIdx.x * 256 + tid;

    // fused coalesced copy of u -> out[0:OUT_U): 393216 threads * 3 float4 = exact
    {
        const float4* __restrict__ u4 = (const float4*)u;
        float4* __restrict__ o4 = (float4*)out;
#pragma unroll
        for (int k = 0; k < 3; ++k) {
            int idx = gid + k * NTHREADS;
            o4[idx] = u4[idx];
        }
    }

    // wave-uniform orientation: waves 0,1 -> o=0; waves 2,3 -> o=1
    const int o  = tid >> 7;
    const int sj = blockIdx.x * 128 + (tid & 127);
    const int j  = sj % 3;
    const int bs = sj / 3;
    const int x  = bs & (NX - 1);

    const float* __restrict__ wbase = w + (size_t)bs * (N_IN * MAT);

    float acc[N_OUT][NCOL][2];
#pragma unroll
    for (int uo = 0; uo < N_OUT; ++uo)
#pragma unroll
        for (int i = 0; i < NCOL; ++i) { acc[uo][i][0] = 0.f; acc[uo][i][1] = 0.f; }

    // term 0 (w itself): o=0 covers channels 0,1; o=1 covers 2,3 (wave-uniform v)
#pragma unroll
    for (int t = 0; t < 2; ++t) {
        const int v = 2 * o + t;
        float4 lo = *(const float4*)&wT[v][0];
        float4 hi = *(const float4*)&wT[v][4];
        const float cw[8] = {lo.x, lo.y, lo.z, lo.w, hi.x, hi.y, hi.z, hi.w};
#pragma unroll
        for (int i = 0; i < NCOL; ++i) {
            float2 e = *(const float2*)(wbase + v * MAT + (i * NCOL + j) * 2);
#pragma unroll
            for (int uo = 0; uo < N_OUT; ++uo) {
                acc[uo][i][0] = fmaf(cw[uo], e.x, acc[uo][i][0]);
                acc[uo][i][1] = fmaf(cw[uo], e.y, acc[uo][i][1]);
            }
        }
    }

    // transported terms (wave-uniform branch, compile-time bodies)
    if (o == 0) do_orientation<0>(x, bs, j, u, w, wT, acc);
    else        do_orientation<1>(x, bs, j, u, w, wT, acc);

    // exchange: each thread ships the output-channel half it does NOT store
    if (o == 0) {
#pragma unroll
        for (int t = 0; t < 4; ++t)
#pragma unroll
            for (int i = 0; i < 3; ++i)
                red[tid][t * 3 + i] = make_float2(acc[4 + t][i][0], acc[4 + t][i][1]);
    } else {
#pragma unroll
        for (int t = 0; t < 4; ++t)
#pragma unroll
            for (int i = 0; i < 3; ++i)
                red[tid][t * 3 + i] = make_float2(acc[t][i][0], acc[t][i][1]);
    }
    __syncthreads();

    const int partner = tid ^ 128;
    float* __restrict__ obase = out + (size_t)OUT_U + (size_t)bs * (N_OUT * MAT);
    float4 idq = *(const float4*)&wT[36][4 * o];
    const float cid[4] = {idq.x, idq.y, idq.z, idq.w};

    if (o == 0) {
        // store channels 0..3 = my acc[0..3] + partner's red
#pragma unroll
        for (int t = 0; t < 4; ++t)
#pragma unroll
            for (int i = 0; i < 3; ++i) {
                float2 r = red[partner][t * 3 + i];
                float2 e;
                e.x = acc[t][i][0] + r.x + ((i == j) ? cid[t] : 0.f);
                e.y = acc[t][i][1] + r.y;
                *(float2*)(obase + t * MAT + (i * NCOL + j) * 2) = e;
            }
    } else {
        // store channels 4..7 = my acc[4..7] + partner's red
#pragma unroll
        for (int t = 0; t < 4; ++t)
#pragma unroll
            for (int i = 0; i < 3; ++i) {
                float2 r = red[partner][t * 3 + i];
                float2 e;
                e.x = acc[4 + t][i][0] + r.x + ((i == j) ? cid[t] : 0.f);
                e.y = acc[4 + t][i][1] + r.y;
                *(float2*)(obase + (4 + t) * MAT + (i * NCOL + j) * 2) = e;
            }
    }
}

} // namespace

extern "C" void kernel_launch(void* const* d_in, const int* in_sizes, int n_in,
                              void* d_out, int out_size, void* d_ws, size_t ws_size,
                              hipStream_t stream)
{
    const float* u   = (const float*)d_in[0];
    const float* w   = (const float*)d_in[1];
    const float* wgt = (const float*)d_in[2];
    float* out = (float*)d_out;

    dim3 block(256);
    dim3 grid(NTHREADS / 256);   // 1536 blocks, exact cover
    lconv_kernel<<<grid, block, 0, stream>>>(u, w, wgt, out);
}